// Round 1
// 492.242 us; speedup vs baseline: 1.0122x; 1.0122x over previous
//
#include <hip/hip_runtime.h>

// ---------------------------------------------------------------------------
// SynthesisLayer (StyleGAN2 modulated conv) on MI355X.
//   s[b,i]   = w[b,:] @ sw[i,:]^T * SS + sb[i]
//   csq[o,i] = CS^2 * sum_t cw[o,i,t]^2
//   sig[b,o] = rsqrt( sum_i s^2[b,i]*csq[o,i] + eps )
//   x'[b,h,w,i] = bf16( x[b,i,h,w] * s[b,i] )
//   cwt[ic,tap,g,o,j] = bf16( cw[o, ic*32+g*8+j, tap]*CS )
//   y = sig * conv(x', cwt) + nw*noise + bias; leaky 0.2
//
// k_conv v2: xs double-buffered in LDS (2 x 40,960 B = 81,920 B -> still
// 2 blocks/CU), stage(ic+1) issued before compute(ic) so the barrier drain
// is free; weight A-fragments loaded per-wave from L2 (no wsm LDS);
// halo columns dropped (predicated zero at image edge); 8-way ch-group
// XOR swizzle (col&3 ^ (col>>2)&3); XCD-chunked block swizzle.
// ---------------------------------------------------------------------------

typedef __attribute__((ext_vector_type(8))) short short8;    // 8 x bf16
typedef __attribute__((ext_vector_type(4))) float f32x4;     // mfma acc

#define STYLE_SCALE 0.044194173824159216f   /* 1/sqrt(512)  */
#define CONV_SCALE  0.014731391274719742f   /* 1/sqrt(4608) */
#define CS2         (1.0f/4608.0f)

static __device__ __forceinline__ unsigned short f2bf(float x) {
    union { float f; unsigned int u; } a; a.f = x;
    unsigned int r = a.u + 0x7fffu + ((a.u >> 16) & 1u);    // round-nearest-even
    return (unsigned short)(r >> 16);
}

static __device__ __forceinline__ void gl_lds16(const void* g, void* l) {
    __builtin_amdgcn_global_load_lds(
        (const __attribute__((address_space(1))) unsigned int*)g,
        (__attribute__((address_space(3))) unsigned int*)l, 16, 0, 0);
}

// ---------------- kernel 1: style linear  s[16,512], split-K x4 -----------
__global__ void k_style(const float* __restrict__ w, const float* __restrict__ sw,
                        const float* __restrict__ sb, float* __restrict__ s) {
    int b = blockIdx.y, j0 = blockIdx.x * 64, t = threadIdx.x;
    __shared__ float wl[512];
    __shared__ float part[256];
    wl[t] = w[b*512 + t]; wl[t+256] = w[b*512 + t + 256];
    __syncthreads();
    int jl = t & 63, seg = t >> 6;
    const float4* row = (const float4*)(sw + (size_t)(j0 + jl)*512) + seg*32;
    const float*  wv  = wl + seg*128;
    float acc = 0.f;
#pragma unroll 4
    for (int k = 0; k < 32; ++k) {
        float4 v = row[k];
        acc += v.x*wv[4*k] + v.y*wv[4*k+1] + v.z*wv[4*k+2] + v.w*wv[4*k+3];
    }
    part[t] = acc;
    __syncthreads();
    if (t < 64)
        s[b*512 + j0 + t] = (part[t] + part[t+64] + part[t+128] + part[t+192])
                            * STYLE_SCALE + sb[j0 + t];
}

// ------- kernel 2: fused csq + weight pack (one cw row per block) ---------
__global__ void k_wprep(const float* __restrict__ cw, float* __restrict__ csq,
                        unsigned short* __restrict__ cwt) {
    int o = blockIdx.x, t = threadIdx.x;
    __shared__ float row[4608];
    const float4* src = (const float4*)(cw + (size_t)o*4608);
    for (int i = t; i < 1152; i += 256) ((float4*)row)[i] = src[i];
    __syncthreads();
    // csq
#pragma unroll
    for (int it = 0; it < 2; ++it) {
        int i = t + it*256;
        float a = 0.f;
#pragma unroll
        for (int k = 0; k < 9; ++k) { float v = row[i*9 + k]; a += v*v; }
        csq[(size_t)o*512 + i] = a * CS2;
    }
    // cwt pack: p = ic*36 + tap*4 + g
    for (int p = t; p < 576; p += 256) {
        int ic = p / 36, rem = p % 36;
        int tap = rem >> 2, g = rem & 3;
        int i0 = ic*32 + g*8;
        union { unsigned short us[8]; uint4 q; } u;
#pragma unroll
        for (int j = 0; j < 8; ++j)
            u.us[j] = f2bf(row[(i0 + j)*9 + tap] * CONV_SCALE);
        *(uint4*)(cwt + ((size_t)p*512 + o)*8) = u.q;
    }
}

// ---------------- kernel 3: sigma[b,o], split-K x4 ------------------------
__global__ void k_sigma(const float* __restrict__ s, const float* __restrict__ csq,
                        float* __restrict__ sig) {
    int b = blockIdx.y, o0 = blockIdx.x * 64, t = threadIdx.x;
    __shared__ float s2l[512];
    __shared__ float part[256];
    float v0 = s[b*512 + t], v1 = s[b*512 + t + 256];
    s2l[t] = v0*v0; s2l[t+256] = v1*v1;
    __syncthreads();
    int ol = t & 63, seg = t >> 6;
    const float4* row = (const float4*)(csq + (size_t)(o0 + ol)*512) + seg*32;
    const float*  sv  = s2l + seg*128;
    float acc = 0.f;
#pragma unroll 4
    for (int k = 0; k < 32; ++k) {
        float4 c = row[k];
        acc += c.x*sv[4*k] + c.y*sv[4*k+1] + c.z*sv[4*k+2] + c.w*sv[4*k+3];
    }
    part[t] = acc;
    __syncthreads();
    if (t < 64)
        sig[b*512 + o0 + t] = 1.0f / sqrtf(part[t] + part[t+64] + part[t+128]
                                           + part[t+192] + 1e-6f);
}

// ------- kernel 4: x' transpose+modulate -> xt[b][h*64+w][c] bf16 ---------
__global__ void k_xt(const float* __restrict__ x, const float* __restrict__ s,
                     unsigned short* __restrict__ xt) {
    int h = blockIdx.x, b = blockIdx.y, t = threadIdx.x;
    __shared__ float tile[64][65];
    __shared__ float sl[64];
    for (int c0 = 0; c0 < 512; c0 += 64) {
        if (t < 64) sl[t] = s[b*512 + c0 + t];
#pragma unroll
        for (int it = 0; it < 4; ++it) {
            int idx = t + it*256;            // [c(64)][w4(16)]
            int c = idx >> 4, w4 = (idx & 15) * 4;
            float4 v = *(const float4*)(x + ((size_t)(b*512 + c0 + c)*4096) + h*64 + w4);
            tile[c][w4]   = v.x; tile[c][w4+1] = v.y;
            tile[c][w4+2] = v.z; tile[c][w4+3] = v.w;
        }
        __syncthreads();
#pragma unroll
        for (int it = 0; it < 2; ++it) {
            int idx = t + it*256;            // [wq(64)][g(8)]
            int wq = idx >> 3, c = (idx & 7) * 8;
            union { unsigned short us[8]; uint4 q; } u;
#pragma unroll
            for (int j = 0; j < 8; ++j)
                u.us[j] = f2bf(tile[c + j][wq] * sl[c + j]);
            *(uint4*)(xt + ((size_t)(b*4096 + h*64 + wq)*512 + c0 + c)) = u.q;
        }
        __syncthreads();
    }
}

// ---------------- kernel 5: implicit-GEMM MFMA conv -----------------------
// block: 64 o x 512 px (8 rows), 4 waves; wave = 64 o x 64 px x 2 rows.
// xs LDS: double-buffered [10 rows][64 cols][4 slots(8ch)] bf16, ch-group
// XOR-swizzled by (col&3)^((col>>2)&3). Halo cols NOT stored: image cols
// -1/64 are zero -> predicated zero on the 2 edge lanes per dx.
// Weights: A-fragments loaded per-wave from global (L2-resident cwt).
// Schedule: stage(ic+1) -> compute(ic) -> syncthreads (drain is free).
__global__ __launch_bounds__(256, 2)
void k_conv(const unsigned short* __restrict__ xt, const unsigned short* __restrict__ cwt,
            const float* __restrict__ sig, const float* __restrict__ nw,
            const float* __restrict__ bias, const float* __restrict__ noise,
            float* __restrict__ out) {
    __shared__ __align__(16) short xs_s[2][20480];      // 2 x 40,960 B = 81,920 B

    const int tid  = threadIdx.x;
    const int lane = tid & 63;
    const int wave = tid >> 6;
    const int quad = lane >> 4;
    const int l15  = lane & 15;

    // XCD-chunked swizzle over flattened 1024-block grid: the 8 oblk
    // siblings (sharing one xt slice) land consecutively on one XCD.
    const int flat = blockIdx.x;
    const int nf   = (flat & 7) * 128 + (flat >> 3);
    const int oblk = nf & 7, pxblk = (nf >> 3) & 7, b = nf >> 6;
    const int o0 = oblk * 64, h0 = pxblk * 8;

    // zero only the out-of-image rows (they are never staged, any ic)
    if (h0 == 0)
        for (int i = tid; i < 1024; i += 256) {
            ((unsigned int*)xs_s[0])[i] = 0u;
            ((unsigned int*)xs_s[1])[i] = 0u;
        }
    if (h0 == 56)
        for (int i = tid; i < 1024; i += 256) {
            ((unsigned int*)xs_s[0])[9*1024 + i] = 0u;
            ((unsigned int*)xs_s[1])[9*1024 + i] = 0u;
        }

    // staging lane decomposition: lane = 4*pp + s writes px p0+pp, slot s;
    // slot s holds ch-group s ^ (p&3) ^ ((p>>2)&3)
    const int pp = lane >> 2;
    const int cg = (lane & 3) ^ (pp & 3) ^ ((pp >> 2) & 3);

#define STAGE(bufidx, icn) do {                                              \
        short* dst_ = xs_s[bufidx];                                          \
        for (int q_ = wave; q_ < 40; q_ += 4) {                              \
            int r_ = q_ >> 2, p0_ = (q_ & 3) << 4;                           \
            int gr_ = h0 - 1 + r_;                                           \
            if (gr_ >= 0 && gr_ < 64)                                        \
                gl_lds16(xt + ((size_t)(b*4096 + gr_*64 + p0_ + pp)*512      \
                               + (icn)*32 + cg*8),                           \
                         dst_ + (r_*64 + p0_)*32);                           \
        } } while (0)

    f32x4 acc[2][4][4];
#pragma unroll
    for (int rr = 0; rr < 2; ++rr)
#pragma unroll
        for (int mt = 0; mt < 4; ++mt)
#pragma unroll
            for (int nt = 0; nt < 4; ++nt) acc[rr][mt][nt] = (f32x4){0.f,0.f,0.f,0.f};

    // per-thread weight base: element [o0 + mt*16 + l15], ch-group quad
    const unsigned short* cwth = cwt + (size_t)quad*4096 + (size_t)(o0 + l15)*8;

    STAGE(0, 0);
    __syncthreads();

    for (int ic = 0; ic < 16; ++ic) {
        if (ic < 15) STAGE((ic + 1) & 1, ic + 1);

        const short8* xp = (const short8*)xs_s[ic & 1];
        const unsigned short* cwA = cwth + (size_t)ic * 147456;   // 36*4096
        const short8 z8 = {};

#define LOADA(dst, tap) do { _Pragma("unroll")                               \
        for (int mt_ = 0; mt_ < 4; ++mt_)                                    \
            dst[mt_] = *(const short8*)(cwA + (size_t)(tap)*16384 + mt_*128);\
        } while (0)

#define TAPSTEP(AF, C0, C1) do { _Pragma("unroll")                           \
        for (int mt_ = 0; mt_ < 4; ++mt_) { _Pragma("unroll")                \
            for (int nt_ = 0; nt_ < 4; ++nt_) {                              \
                acc[0][mt_][nt_] = __builtin_amdgcn_mfma_f32_16x16x32_bf16(  \
                    AF[mt_], C0[nt_], acc[0][mt_][nt_], 0, 0, 0);            \
                acc[1][mt_][nt_] = __builtin_amdgcn_mfma_f32_16x16x32_bf16(  \
                    AF[mt_], C1[nt_], acc[1][mt_][nt_], 0, 0, 0);            \
            } } } while (0)

#pragma unroll
        for (int dx = 0; dx < 3; ++dx) {
            // cs = (image col of nt=1 fragment) = l15 + dx - 1 + 16
            const int cs   = l15 + dx + 15;
            const int slot = quad ^ (cs & 3) ^ ((cs >> 2) & 3);  // nt-invariant
            const int colS = cs*4 + slot;                        // slot units

            // base_ points at col ci+16; nt cols = base_-64, base_, +64, +128
#define LOADB(bf, d) do {                                                    \
            const int base_ = (2*wave + (d))*256 + colS;                     \
            if (dx == 0) {                                                   \
                int a0_ = (l15 == 0) ? base_ : base_ - 64;                   \
                bf[0] = xp[a0_];        bf[1] = xp[base_];                   \
                bf[2] = xp[base_ + 64]; bf[3] = xp[base_ + 128];             \
                if (l15 == 0) bf[0] = z8;                                    \
            } else if (dx == 1) {                                            \
                bf[0] = xp[base_ - 64]; bf[1] = xp[base_];                   \
                bf[2] = xp[base_ + 64]; bf[3] = xp[base_ + 128];             \
            } else {                                                         \
                int a3_ = (l15 == 15) ? base_ : base_ + 128;                 \
                bf[0] = xp[base_ - 64]; bf[1] = xp[base_];                   \
                bf[2] = xp[base_ + 64]; bf[3] = xp[a3_];                     \
                if (l15 == 15) bf[3] = z8;                                   \
            }                                                                \
        } while (0)

            short8 afA[4], afB[4], bA[4], bB[4];
            LOADA(afA, dx);            // tap dy=0
            LOADA(afB, dx + 3);        // tap dy=1
            LOADB(bA, 0);              // xs row 2w
            LOADB(bB, 1);              // xs row 2w+1
            TAPSTEP(afA, bA, bB);
            LOADA(afA, dx + 6);        // tap dy=2 (reuse regs)
            LOADB(bA, 2);              // xs row 2w+2
            TAPSTEP(afB, bB, bA);
            LOADB(bB, 3);              // xs row 2w+3
            TAPSTEP(afA, bA, bB);
#undef LOADB
        }
#undef LOADA
#undef TAPSTEP
        __syncthreads();   // drains staged gl_lds (already landed under compute)
    }
#undef STAGE

    // ---- epilogue: sigma scale + noise + bias + leaky relu ----
    float nz[2][4];
#pragma unroll
    for (int rr = 0; rr < 2; ++rr) {
        int h = h0 + 2*wave + rr;
#pragma unroll
        for (int nt = 0; nt < 4; ++nt) nz[rr][nt] = noise[b*4096 + h*64 + nt*16 + l15];
    }
#pragma unroll
    for (int mt = 0; mt < 4; ++mt) {
#pragma unroll
        for (int r = 0; r < 4; ++r) {
            int o = o0 + mt*16 + quad*4 + r;
            float sg  = sig[b*512 + o];
            float nwv = nw[o], bv = bias[o];
#pragma unroll
            for (int rr = 0; rr < 2; ++rr) {
                int h = h0 + 2*wave + rr;
#pragma unroll
                for (int nt = 0; nt < 4; ++nt) {
                    float v = acc[rr][mt][nt][r] * sg + nwv * nz[rr][nt] + bv;
                    v = (v >= 0.f) ? v : 0.2f * v;
                    out[((size_t)(b*512 + o)*4096) + h*64 + nt*16 + l15] = v;
                }
            }
        }
    }
}

// ---------------------------------------------------------------------------
extern "C" void kernel_launch(void* const* d_in, const int* in_sizes, int n_in,
                              void* d_out, int out_size, void* d_ws, size_t ws_size,
                              hipStream_t stream) {
    const float* x     = (const float*)d_in[0];
    const float* w     = (const float*)d_in[1];
    const float* sw    = (const float*)d_in[2];
    const float* sb    = (const float*)d_in[3];
    const float* cw    = (const float*)d_in[4];
    const float* nw    = (const float*)d_in[5];
    const float* bias  = (const float*)d_in[6];
    const float* noise = (const float*)d_in[7];
    float* out = (float*)d_out;

    char* ws = (char*)d_ws;
    unsigned short* xt  = (unsigned short*)(ws + 0);          // 67,108,864 B
    unsigned short* cwt = (unsigned short*)(ws + 67108864);   //  4,718,592 B
    float* s   = (float*)(ws + 71827456);                     //     32,768 B
    float* sig = (float*)(ws + 71860224);                     //     32,768 B
    float* csq = (float*)(ws + 71892992);                     //  1,048,576 B

    k_wprep<<<512, 256, 0, stream>>>(cw, csq, cwt);
    k_style<<<dim3(8, 16), 256, 0, stream>>>(w, sw, sb, s);
    k_sigma<<<dim3(8, 16), 256, 0, stream>>>(s, csq, sig);
    k_xt   <<<dim3(64, 16), 256, 0, stream>>>(x, s, xt);
    k_conv <<<dim3(1024), 256, 0, stream>>>(xt, cwt, sig, nw, bias, noise, out);
}